// Round 10
// baseline (378.023 us; speedup 1.0000x reference)
//
#include <hip/hip_runtime.h>
#include <stdint.h>
#include <math.h>

static constexpr int NIMG  = 16;
static constexpr int HH    = 512;
static constexpr int WW    = 512;
static constexpr int TOTAL = NIMG * HH * WW;   // 4,194,304
static constexpr int WPR   = WW / 64;          // 8 qwords per row
static constexpr int QPI   = HH * WPR;         // 4096 qwords per image
static constexpr int NQ    = TOTAL / 64;       // 65,536
static constexpr int MAXIT = 128;
static constexpr int SW    = 9;                // padded LDS row stride (72B), col 8 unused (bank skew)
static constexpr int RBLK  = 1024;             // reduce blocks
static constexpr int FW    = 10;               // dirty-flag array row stride (margins)

// workspace layout (bytes)
static constexpr size_t OFF_PACK = 0;                      // u64[NQ] converged mask
static constexpr size_t OFF_PART = (size_t)NQ * 8;         // double[RBLK*2]

// gaussian taps exactly like numpy (f64 exp, sequential /sum, cast f32) — bit-compatible (r5-r9: absmax 0)
__device__ __forceinline__ void make_gk(float* gks) {
    if (threadIdx.x < 9) {
        double ssum = 0.0;
        for (int i = 0; i < 9; ++i) { double x = (double)(i - 4); ssum += exp(-0.5 * x * x); }
        double x = (double)((int)threadIdx.x - 4);
        gks[threadIdx.x] = (float)(exp(-0.5 * x * x) / ssum);
    }
}

// full adder on 64 bit-lanes
__device__ __forceinline__ void fa(uint64_t a, uint64_t b, uint64_t c, uint64_t& s, uint64_t& cy) {
    uint64_t axb = a ^ b;
    s  = axb ^ c;
    cy = (a & b) | (c & axb);
}

// bit-sliced Zhang-Suen delete mask (verified exact, rounds 2-9)
__device__ __forceinline__ uint64_t zs_del(uint64_t cc, uint64_t nc, uint64_t sc, uint64_t cw, uint64_t ce,
                                           uint64_t nw, uint64_t ne, uint64_t sw, uint64_t se, int step) {
    uint64_t p2 = nc;
    uint64_t p3 = (nc >> 1) | (ne << 63);
    uint64_t p4 = (cc >> 1) | (ce << 63);
    uint64_t p5 = (sc >> 1) | (se << 63);
    uint64_t p6 = sc;
    uint64_t p7 = (sc << 1) | (sw >> 63);
    uint64_t p8 = (cc << 1) | (cw >> 63);
    uint64_t p9 = (nc << 1) | (nw >> 63);

    uint64_t s1, k1, s2, k2;
    fa(p2, p3, p4, s1, k1);
    fa(p5, p6, p7, s2, k2);
    uint64_t s3 = p8 ^ p9, k3 = p8 & p9;
    uint64_t b0, k4;
    fa(s1, s2, s3, b0, k4);
    uint64_t t1, t2;
    fa(k1, k2, k3, t1, t2);
    uint64_t b1 = t1 ^ k4;
    uint64_t k5 = t1 & k4;
    uint64_t b2 = t2 ^ k5;
    uint64_t b3 = t2 & k5;
    uint64_t condB = (b1 | b2 | b3) & ~(b3 | (b0 & b1 & b2));

    uint64_t q0 = ~p2 & p3, q1 = ~p3 & p4, q2 = ~p4 & p5, q3 = ~p5 & p6;
    uint64_t q4 = ~p6 & p7, q5 = ~p7 & p8, q6 = ~p8 & p9, q7 = ~p9 & p2;
    uint64_t u1, v1, u2, v2;
    fa(q0, q1, q2, u1, v1);
    fa(q3, q4, q5, u2, v2);
    uint64_t u3 = q6 ^ q7, v3 = q6 & q7;
    uint64_t a0, v4;
    fa(u1, u2, u3, a0, v4);
    uint64_t w1, w2;
    fa(v1, v2, v3, w1, w2);
    uint64_t a1 = w1 ^ v4;
    uint64_t ka = w1 & v4;
    uint64_t a2 = w2 ^ ka;
    uint64_t a3 = w2 & ka;
    uint64_t condA = a0 & ~a1 & ~a2 & ~a3;

    uint64_t nc1, nc2;
    if (step == 0) { nc1 = ~(p2 & p4 & p6); nc2 = ~(p4 & p6 & p8); }
    else           { nc1 = ~(p2 & p4 & p8); nc2 = ~(p2 & p6 & p8); }

    return cc & condB & condA & nc1 & nc2;
}

// one sub-step: thread walks a 4-row column, rotating row registers (r8 version, measured 50us/24 substeps)
__device__ __forceinline__ int zs_sub(const uint64_t* __restrict__ cur, uint64_t* __restrict__ nxt,
                                      int step, int wx, int y0, bool xw, bool xe) {
    int ch = 0;
    int b = y0 * SW + wx;
    uint64_t nwr, ncr, ner, cwr, ccr, cer;
    if (y0 > 0) {
        ncr = cur[b - SW];
        nwr = xw ? cur[b - SW - 1] : 0;
        ner = xe ? cur[b - SW + 1] : 0;
    } else { nwr = 0; ncr = 0; ner = 0; }
    ccr = cur[b];
    cwr = xw ? cur[b - 1] : 0;
    cer = xe ? cur[b + 1] : 0;
#pragma unroll
    for (int r = 0; r < 4; ++r) {
        uint64_t swr, scr, ser;
        if (y0 + r < HH - 1) {
            scr = cur[b + SW];
            swr = xw ? cur[b + SW - 1] : 0;
            ser = xe ? cur[b + SW + 1] : 0;
        } else { swr = 0; scr = 0; ser = 0; }
        uint64_t out = ccr;
        if (ccr) {
            uint64_t del = zs_del(ccr, ncr, scr, cwr, cer, nwr, ner, swr, ser, step);
            out = ccr & ~del;
            ch |= (del != 0ull);
        }
        nxt[b] = out;
        nwr = cwr; ncr = ccr; ner = cer;
        cwr = swr; ccr = scr; cer = ser;
        b += SW;
    }
    return ch;
}

// 9-cell neighborhood max of lastch (margins stay 0 = "changed at substep 0")
__device__ __forceinline__ int nb_max(const int* __restrict__ lastch, int fidx) {
    int m0 = max(max(lastch[fidx - FW - 1], lastch[fidx - FW]), lastch[fidx - FW + 1]);
    int m1 = max(max(lastch[fidx - 1],      lastch[fidx]),      lastch[fidx + 1]);
    int m2 = max(max(lastch[fidx + FW - 1], lastch[fidx + FW]), lastch[fidx + FW + 1]);
    return max(max(m0, m1), m2);
}

// --- fused blur + thinning: one block per image (1024 threads).
// Phase 1: separable blur/threshold/pack straight into LDS SA (64 sequential 64x64 tiles).
// Phase 2: ZS thinning to convergence with dirty-region skipping; write mask to global for reduce.
__global__ void __launch_bounds__(1024) blur_skel(const float* __restrict__ gt,
                                                  uint64_t* __restrict__ packed) {
    __shared__ uint64_t SA[HH * SW];   // 36,864 B
    __shared__ uint64_t SB[HH * SW];   // 36,864 B
    __shared__ float tin[72 * 72];     // 20,736 B (blur scratch)
    __shared__ float tv[64 * 72];      // 18,432 B
    __shared__ float gks[9];
    __shared__ int lastch[130 * FW];   // 5,200 B dirty flags (+ zero margins)
    __shared__ int f2[2];
    const int tid = threadIdx.x;
    const int img = blockIdx.x;
    make_gk(gks);

    // ---- Phase 1: blur this image into SA (packed bits) ----
    const float* G = gt + (size_t)img * (HH * WW);
    const int lane = tid & 63, w = tid >> 6;      // 16 warps
    for (int tile = 0; tile < 64; ++tile) {
        const int oy = (tile >> 3) << 6, ox = (tile & 7) << 6;
        for (int i = tid; i < 72 * 72; i += 1024) {
            int r = i / 72, c = i - r * 72;
            int gy = oy - 4 + r, gx = ox - 4 + c;
            gy = gy < 0 ? -gy - 1 : (gy >= HH ? 2 * HH - 1 - gy : gy);   // symmetric pad
            gx = gx < 0 ? -gx - 1 : (gx >= WW ? 2 * WW - 1 - gx : gx);
            tin[i] = G[gy * WW + gx];
        }
        __syncthreads();
        for (int i = tid; i < 64 * 72; i += 1024) {   // vertical pass first (axis=1, like ref)
            int r = i / 72, c = i - r * 72;
            float s = 0.f;
#pragma unroll
            for (int t = 0; t < 9; ++t) s += gks[t] * tin[(r + t) * 72 + c];
            tv[i] = s;
        }
        __syncthreads();
#pragma unroll
        for (int jj = 0; jj < 4; ++jj) {              // horizontal pass + threshold + pack
            int yr = (w << 2) | jj;
            float s = 0.f;
#pragma unroll
            for (int t = 0; t < 9; ++t) s += gks[t] * tv[yr * 72 + lane + t];
            uint64_t m = __ballot(s > 0.1f);
            if (lane == 0) SA[(oy + yr) * SW + (ox >> 6)] = m;
        }
        __syncthreads();                              // SA tile rows done; tin reusable
    }

    // ---- Phase 2: thinning with dirty-region skip ----
    for (int i = tid; i < 130 * FW; i += 1024) lastch[i] = 0;
    if (tid == 0) { f2[0] = 0; f2[1] = 0; }
    __syncthreads();

    const int wx = tid & 7;
    const int g  = tid >> 3;            // cell = 4-row column
    const int y0 = g * 4;
    const bool xw = wx > 0, xe = wx < WPR - 1;
    const int fidx = (g + 1) * FW + wx + 1;

    for (int it = 0; it < MAXIT; ++it) {
        const int p  = it & 1;
        const int j1 = 2 * it + 1, j2 = 2 * it + 2;
        int ch1 = 0, ch2 = 0;
        // substep j1 (rule 0): SA -> SB. Skip iff no 3x3 neighbor changed in substeps j1-1, j1-2.
        if (nb_max(lastch, fidx) >= j1 - 2) {
            ch1 = zs_sub(SA, SB, 0, wx, y0, xw, xe);
            if (ch1) lastch[fidx] = j1;
        }
        __syncthreads();                         // SB + lastch(j1) complete; f2[p^1] reset visible
        // substep j2 (rule 1): SB -> SA
        if (nb_max(lastch, fidx) >= j2 - 2) {
            ch2 = zs_sub(SB, SA, 1, wx, y0, xw, xe);
            if (ch2) lastch[fidx] = j2;
        }
        if (__any(ch1 | ch2) && (tid & 63) == 0) atomicOr(&f2[p], 1);
        __syncthreads();                         // SA + lastch(j2) + f2[p] complete
        int stop = (f2[p] == 0);                 // uniform
        if (tid == 0) f2[p ^ 1] = 0;             // reset other parity; ordered by next iter's barrier
        if (stop) break;
    }
    // SA holds the converged mask; publish for the reduce kernel
    uint64_t* gimg = packed + (size_t)img * QPI;
    for (int i = tid; i < QPI; i += 1024) gimg[i] = SA[(i >> 3) * SW + (i & 7)];
}

// --- loss reduction: per-block f64 partials, unconditional writes, NO cross-block coordination (r8)
__global__ void __launch_bounds__(256) reduce_kernel(const float4* __restrict__ pred4, const float4* __restrict__ gt4,
                                                     const uint64_t* __restrict__ mask,
                                                     double* __restrict__ part) {
    __shared__ double sh0[256];
    __shared__ double sh1[256];
    const int tid = threadIdx.x;
    double a0 = 0.0, a1 = 0.0;
    const int N4 = TOTAL / 4;
    for (int i = blockIdx.x * 256 + tid; i < N4; i += RBLK * 256) {
        float4 pv = pred4[i];
        float4 gv = gt4[i];
        uint64_t mq = mask[i >> 4];
        int shb = (i & 15) << 2;
        double d, d2;
        d = (double)(pv.x - gv.x); d2 = d * d; a0 += d2; if ((mq >> (shb    )) & 1) a1 += d2;
        d = (double)(pv.y - gv.y); d2 = d * d; a0 += d2; if ((mq >> (shb + 1)) & 1) a1 += d2;
        d = (double)(pv.z - gv.z); d2 = d * d; a0 += d2; if ((mq >> (shb + 2)) & 1) a1 += d2;
        d = (double)(pv.w - gv.w); d2 = d * d; a0 += d2; if ((mq >> (shb + 3)) & 1) a1 += d2;
    }
    sh0[tid] = a0;
    sh1[tid] = a1;
    __syncthreads();
    for (int off = 128; off > 0; off >>= 1) {
        if (tid < off) { sh0[tid] += sh0[tid + off]; sh1[tid] += sh1[tid + off]; }
        __syncthreads();
    }
    if (tid == 0) {
        part[2 * blockIdx.x]     = sh0[0];
        part[2 * blockIdx.x + 1] = sh1[0];
    }
}

// --- single-block finalize: sum RBLK*2 doubles, write the loss
__global__ void __launch_bounds__(256) finalize_kernel(const double* __restrict__ part,
                                                       float* __restrict__ out) {
    __shared__ double sh[256];
    const int tid = threadIdx.x;
    double a = 0.0;
    for (int i = tid; i < RBLK; i += 256) a += part[2 * i] + part[2 * i + 1];
    sh[tid] = a;
    __syncthreads();
    for (int off = 128; off > 0; off >>= 1) {
        if (tid < off) sh[tid] += sh[tid + off];
        __syncthreads();
    }
    if (tid == 0) out[0] = (float)(0.5 * sh[0] / (double)TOTAL);
}

extern "C" void kernel_launch(void* const* d_in, const int* in_sizes, int n_in,
                              void* d_out, int out_size, void* d_ws, size_t ws_size,
                              hipStream_t stream) {
    const float* pred = (const float*)d_in[0];
    const float* gt   = (const float*)d_in[1];
    char* ws = (char*)d_ws;
    uint64_t* packed = (uint64_t*)(ws + OFF_PACK);
    double*   part   = (double*)(ws + OFF_PART);

    blur_skel<<<NIMG, 1024, 0, stream>>>(gt, packed);
    reduce_kernel<<<RBLK, 256, 0, stream>>>((const float4*)pred, (const float4*)gt, packed, part);
    finalize_kernel<<<1, 256, 0, stream>>>(part, (float*)d_out);
}

// Round 11
// 162.823 us; speedup vs baseline: 2.3217x; 2.3217x over previous
//
#include <hip/hip_runtime.h>
#include <stdint.h>
#include <math.h>

static constexpr int NIMG  = 16;
static constexpr int HH    = 512;
static constexpr int WW    = 512;
static constexpr int TOTAL = NIMG * HH * WW;   // 4,194,304
static constexpr int WPR   = WW / 64;          // 8 qwords per row
static constexpr int QPI   = HH * WPR;         // 4096 qwords per image
static constexpr int NQ    = TOTAL / 64;       // 65,536
static constexpr int MAXIT = 128;
static constexpr int SW    = 9;                // padded LDS row stride (72B: 2-way banks, free)
static constexpr int FW    = 10;               // dirty-flag row stride (zero margins)
static constexpr int ABLK  = 1024;             // blur/a0 blocks
static constexpr int GBLK  = 64;               // a1 gather blocks (x1024 threads = 1 qword/thread)

// workspace layout (bytes)
static constexpr size_t OFF_PACK = 0;                       // u64[NQ] packed bitmap / converged mask
static constexpr size_t OFF_A0   = (size_t)NQ * 8;          // double[ABLK]
static constexpr size_t OFF_A1   = OFF_A0 + (size_t)ABLK * 8;  // double[GBLK]
static constexpr size_t OFF_TICK = OFF_A1 + (size_t)GBLK * 8;  // int

#define LD_RLX(p)   __hip_atomic_load((p), __ATOMIC_RELAXED, __HIP_MEMORY_SCOPE_AGENT)
#define ST_RLX(p,v) __hip_atomic_store((p), (v), __ATOMIC_RELAXED, __HIP_MEMORY_SCOPE_AGENT)

// gaussian taps exactly like numpy (f64 exp, sequential /sum, cast f32) — bit-compatible (r5-r10: absmax 0)
__device__ __forceinline__ void make_gk(float* gks) {
    if (threadIdx.x < 9) {
        double ssum = 0.0;
        for (int i = 0; i < 9; ++i) { double x = (double)(i - 4); ssum += exp(-0.5 * x * x); }
        double x = (double)((int)threadIdx.x - 4);
        gks[threadIdx.x] = (float)(exp(-0.5 * x * x) / ssum);
    }
}

// --- fused blur + threshold + pack + unmasked-loss partial. 64x64 tile per block (1024 blocks).
__global__ void __launch_bounds__(256) blur_a0(const float* __restrict__ gt,
                                               const float4* __restrict__ pred4,
                                               uint64_t* __restrict__ packed,
                                               double* __restrict__ part_a0,
                                               int* __restrict__ tick) {
    __shared__ float tin[72 * 72];
    __shared__ float tv[64 * 72];
    __shared__ float gks[9];
    __shared__ double sh[256];
    const int tid = threadIdx.x;
    if (blockIdx.x == 0 && tid == 0) *tick = 0;      // ws re-poisoned before every timed call
    make_gk(gks);
    const int img  = blockIdx.x >> 6;
    const int tile = blockIdx.x & 63;
    const int oy = (tile >> 3) << 6, ox = (tile & 7) << 6;
    const float* G = gt + (size_t)img * (HH * WW);
    for (int i = tid; i < 72 * 72; i += 256) {
        int r = i / 72, c = i - r * 72;
        int gy = oy - 4 + r, gx = ox - 4 + c;
        gy = gy < 0 ? -gy - 1 : (gy >= HH ? 2 * HH - 1 - gy : gy);   // symmetric pad
        gx = gx < 0 ? -gx - 1 : (gx >= WW ? 2 * WW - 1 - gx : gx);
        tin[i] = G[gy * WW + gx];
    }
    __syncthreads();
    for (int i = tid; i < 64 * 72; i += 256) {       // vertical pass first (axis=1, like ref)
        int r = i / 72, c = i - r * 72;
        float s = 0.f;
#pragma unroll
        for (int t = 0; t < 9; ++t) s += gks[t] * tin[(r + t) * 72 + c];
        tv[i] = s;
    }
    __syncthreads();
    const int lane = tid & 63, w = tid >> 6;
    for (int j = 0; j < 16; ++j) {                   // horizontal pass + threshold + pack
        int yr = w * 16 + j;
        float s = 0.f;
#pragma unroll
        for (int t = 0; t < 9; ++t) s += gks[t] * tv[yr * 72 + lane + t];
        uint64_t m = __ballot(s > 0.1f);
        if (lane == 0) packed[(size_t)img * QPI + (oy + yr) * WPR + (ox >> 6)] = m;
    }
    // --- unmasked loss partial over this 64x64 tile (gt from tin interior, pred streamed)
    double a0 = 0.0;
    for (int i = tid; i < 1024; i += 256) {          // 64 rows x 16 float4
        int r = i >> 4, c4 = i & 15;
        float4 pv = pred4[(size_t)img * (HH * WW / 4) + (size_t)(oy + r) * (WW / 4) + (ox >> 2) + c4];
        const float* gv = &tin[(r + 4) * 72 + c4 * 4 + 4];
        double d;
        d = (double)(pv.x - gv[0]); a0 += d * d;
        d = (double)(pv.y - gv[1]); a0 += d * d;
        d = (double)(pv.z - gv[2]); a0 += d * d;
        d = (double)(pv.w - gv[3]); a0 += d * d;
    }
    sh[tid] = a0;
    __syncthreads();
    for (int off = 128; off > 0; off >>= 1) {
        if (tid < off) sh[tid] += sh[tid + off];
        __syncthreads();
    }
    if (tid == 0) part_a0[blockIdx.x] = sh[0];
}

// full adder on 64 bit-lanes
__device__ __forceinline__ void fa(uint64_t a, uint64_t b, uint64_t c, uint64_t& s, uint64_t& cy) {
    uint64_t axb = a ^ b;
    s  = axb ^ c;
    cy = (a & b) | (c & axb);
}

// bit-sliced Zhang-Suen delete mask (verified exact, rounds 2-10)
__device__ __forceinline__ uint64_t zs_del(uint64_t cc, uint64_t nc, uint64_t sc, uint64_t cw, uint64_t ce,
                                           uint64_t nw, uint64_t ne, uint64_t sw, uint64_t se, int step) {
    uint64_t p2 = nc;
    uint64_t p3 = (nc >> 1) | (ne << 63);
    uint64_t p4 = (cc >> 1) | (ce << 63);
    uint64_t p5 = (sc >> 1) | (se << 63);
    uint64_t p6 = sc;
    uint64_t p7 = (sc << 1) | (sw >> 63);
    uint64_t p8 = (cc << 1) | (cw >> 63);
    uint64_t p9 = (nc << 1) | (nw >> 63);

    uint64_t s1, k1, s2, k2;
    fa(p2, p3, p4, s1, k1);
    fa(p5, p6, p7, s2, k2);
    uint64_t s3 = p8 ^ p9, k3 = p8 & p9;
    uint64_t b0, k4;
    fa(s1, s2, s3, b0, k4);
    uint64_t t1, t2;
    fa(k1, k2, k3, t1, t2);
    uint64_t b1 = t1 ^ k4;
    uint64_t k5 = t1 & k4;
    uint64_t b2 = t2 ^ k5;
    uint64_t b3 = t2 & k5;
    uint64_t condB = (b1 | b2 | b3) & ~(b3 | (b0 & b1 & b2));

    uint64_t q0 = ~p2 & p3, q1 = ~p3 & p4, q2 = ~p4 & p5, q3 = ~p5 & p6;
    uint64_t q4 = ~p6 & p7, q5 = ~p7 & p8, q6 = ~p8 & p9, q7 = ~p9 & p2;
    uint64_t u1, v1, u2, v2;
    fa(q0, q1, q2, u1, v1);
    fa(q3, q4, q5, u2, v2);
    uint64_t u3 = q6 ^ q7, v3 = q6 & q7;
    uint64_t a0, v4;
    fa(u1, u2, u3, a0, v4);
    uint64_t w1, w2;
    fa(v1, v2, v3, w1, w2);
    uint64_t a1 = w1 ^ v4;
    uint64_t ka = w1 & v4;
    uint64_t a2 = w2 ^ ka;
    uint64_t a3 = w2 & ka;
    uint64_t condA = a0 & ~a1 & ~a2 & ~a3;

    uint64_t nc1, nc2;
    if (step == 0) { nc1 = ~(p2 & p4 & p6); nc2 = ~(p4 & p6 & p8); }
    else           { nc1 = ~(p2 & p4 & p8); nc2 = ~(p2 & p6 & p8); }

    return cc & condB & condA & nc1 & nc2;
}

// one sub-step: thread walks a 4-row column, rotating row registers (r8 version)
__device__ __forceinline__ int zs_sub(const uint64_t* __restrict__ cur, uint64_t* __restrict__ nxt,
                                      int step, int wx, int y0, bool xw, bool xe) {
    int ch = 0;
    int b = y0 * SW + wx;
    uint64_t nwr, ncr, ner, cwr, ccr, cer;
    if (y0 > 0) {
        ncr = cur[b - SW];
        nwr = xw ? cur[b - SW - 1] : 0;
        ner = xe ? cur[b - SW + 1] : 0;
    } else { nwr = 0; ncr = 0; ner = 0; }
    ccr = cur[b];
    cwr = xw ? cur[b - 1] : 0;
    cer = xe ? cur[b + 1] : 0;
#pragma unroll
    for (int r = 0; r < 4; ++r) {
        uint64_t swr, scr, ser;
        if (y0 + r < HH - 1) {
            scr = cur[b + SW];
            swr = xw ? cur[b + SW - 1] : 0;
            ser = xe ? cur[b + SW + 1] : 0;
        } else { swr = 0; scr = 0; ser = 0; }
        uint64_t out = ccr;
        if (ccr) {
            uint64_t del = zs_del(ccr, ncr, scr, cwr, cer, nwr, ner, swr, ser, step);
            out = ccr & ~del;
            ch |= (del != 0ull);
        }
        nxt[b] = out;
        nwr = cwr; ncr = ccr; ner = cer;
        cwr = swr; ccr = scr; cer = ser;
        b += SW;
    }
    return ch;
}

// 9-cell neighborhood max of lastch (margins stay 0 = "changed at substep 0")
__device__ __forceinline__ int nb_max(const int* __restrict__ lastch, int fidx) {
    int m0 = max(max(lastch[fidx - FW - 1], lastch[fidx - FW]), lastch[fidx - FW + 1]);
    int m1 = max(max(lastch[fidx - 1],      lastch[fidx]),      lastch[fidx + 1]);
    int m2 = max(max(lastch[fidx + FW - 1], lastch[fidx + FW]), lastch[fidx + FW + 1]);
    return max(max(m0, m1), m2);
}

// --- one workgroup per image; thinning in LDS with dirty-region skip (skip logic HW-validated r10)
__global__ void __launch_bounds__(1024) skel_kernel(uint64_t* __restrict__ g) {
    __shared__ uint64_t SA[HH * SW];   // 36,864 B
    __shared__ uint64_t SB[HH * SW];
    __shared__ int lastch[130 * FW];   // 5,200 B dirty flags (+ zero margins)
    __shared__ int f2[2];
    const int tid = threadIdx.x;
    uint64_t* gimg = g + (size_t)blockIdx.x * QPI;

    for (int i = tid; i < QPI; i += 1024) SA[(i >> 3) * SW + (i & 7)] = gimg[i];
    for (int i = tid; i < 130 * FW; i += 1024) lastch[i] = 0;
    if (tid == 0) { f2[0] = 0; f2[1] = 0; }
    __syncthreads();

    const int wx = tid & 7;
    const int g4 = tid >> 3;           // cell = 4-row column
    const int y0 = g4 * 4;
    const bool xw = wx > 0, xe = wx < WPR - 1;
    const int fidx = (g4 + 1) * FW + wx + 1;

    for (int it = 0; it < MAXIT; ++it) {
        const int p  = it & 1;
        const int j1 = 2 * it + 1, j2 = 2 * it + 2;
        int ch1 = 0, ch2 = 0;
        // substep j1 (rule 0): SA -> SB. Skip iff no 3x3 neighbor changed in substeps j1-1, j1-2
        // (then input neighborhood == 2 substeps ago, same rule parity -> SB already correct).
        if (nb_max(lastch, fidx) >= j1 - 2) {
            ch1 = zs_sub(SA, SB, 0, wx, y0, xw, xe);
            if (ch1) lastch[fidx] = j1;
        }
        __syncthreads();                         // SB + lastch(j1) complete; f2[p^1] reset visible
        if (nb_max(lastch, fidx) >= j2 - 2) {    // substep j2 (rule 1): SB -> SA
            ch2 = zs_sub(SB, SA, 1, wx, y0, xw, xe);
            if (ch2) lastch[fidx] = j2;
        }
        if (__any(ch1 | ch2) && (tid & 63) == 0) atomicOr(&f2[p], 1);
        __syncthreads();                         // SA + lastch(j2) + f2[p] complete
        int stop = (f2[p] == 0);                 // uniform
        if (tid == 0) f2[p ^ 1] = 0;             // reset other parity; ordered by next iter's barrier
        if (stop) break;
    }

    for (int i = tid; i < QPI; i += 1024) gimg[i] = SA[(i >> 3) * SW + (i & 7)];
}

// --- masked-loss gather + finalize: 1 qword/thread, ctz over set bits, 64-way ticket, last block sums all
__global__ void __launch_bounds__(1024) a1_fin(const float* __restrict__ pred, const float* __restrict__ gtf,
                                               const uint64_t* __restrict__ mask,
                                               const double* __restrict__ part_a0,
                                               double* __restrict__ part_a1,
                                               int* __restrict__ tick,
                                               float* __restrict__ out) {
    __shared__ double sh[1024];
    __shared__ int lastf;
    const int tid = threadIdx.x;
    const int q = blockIdx.x * 1024 + tid;       // [0, NQ)
    double a1 = 0.0;
    uint64_t mq = mask[q];
    const int base = q << 6;
    while (mq) {
        int b = __builtin_ctzll(mq);
        mq &= mq - 1;
        int idx = base + b;
        double d = (double)(pred[idx] - gtf[idx]);
        a1 += d * d;
    }
    sh[tid] = a1;
    __syncthreads();
    for (int off = 512; off > 0; off >>= 1) {
        if (tid < off) sh[tid] += sh[tid + off];
        __syncthreads();
    }
    if (tid == 0) {
        ST_RLX(&part_a1[blockIdx.x], sh[0]);
        int pos = __hip_atomic_fetch_add(tick, 1, __ATOMIC_ACQ_REL, __HIP_MEMORY_SCOPE_AGENT);
        lastf = (pos == GBLK - 1);               // acq sees earlier blocks' rel-ordered partials
    }
    __syncthreads();
    if (lastf) {
        double a = LD_RLX(&part_a0[tid]);        // ABLK == 1024 partials, one per thread
        if (tid < GBLK) a += LD_RLX(&part_a1[tid]);
        sh[tid] = a;
        __syncthreads();
        for (int off = 512; off > 0; off >>= 1) {
            if (tid < off) sh[tid] += sh[tid + off];
            __syncthreads();
        }
        if (tid == 0) out[0] = (float)(0.5 * sh[0] / (double)TOTAL);
    }
}

extern "C" void kernel_launch(void* const* d_in, const int* in_sizes, int n_in,
                              void* d_out, int out_size, void* d_ws, size_t ws_size,
                              hipStream_t stream) {
    const float* pred = (const float*)d_in[0];
    const float* gt   = (const float*)d_in[1];
    char* ws = (char*)d_ws;
    uint64_t* packed  = (uint64_t*)(ws + OFF_PACK);
    double*   part_a0 = (double*)(ws + OFF_A0);
    double*   part_a1 = (double*)(ws + OFF_A1);
    int*      tick    = (int*)(ws + OFF_TICK);

    blur_a0<<<ABLK, 256, 0, stream>>>(gt, (const float4*)pred, packed, part_a0, tick);
    skel_kernel<<<NIMG, 1024, 0, stream>>>(packed);
    a1_fin<<<GBLK, 1024, 0, stream>>>(pred, gt, packed, part_a0, part_a1, tick, (float*)d_out);
}